// Round 1
// baseline (19720.270 us; speedup 1.0000x reference)
//
#include <hip/hip_runtime.h>
#include <math.h>

#define BB 2
#define DD 768
#define HH 16
#define HDIM 48
#define LL 3
#define NIMG 1024
#define NPAST 16
#define TDEC 20
#define SEQ0 1041
#define SPAD 1064
#define MM (BB*SEQ0)
#define SCALE_QK 0.14433756729740643f

// ---------------- utils ----------------
__device__ __forceinline__ float block_sum256(float v, float* red) {
#pragma unroll
  for (int off = 32; off; off >>= 1) v += __shfl_down(v, off);
  __syncthreads();
  if ((threadIdx.x & 63) == 0) red[threadIdx.x >> 6] = v;
  __syncthreads();
  return red[0] + red[1] + red[2] + red[3];
}

// ---------------- build sequence ----------------
__global__ __launch_bounds__(256) void build_img_kernel(
    const float* __restrict__ feats, const float* __restrict__ pe, float* __restrict__ x)
{
  __shared__ float T[64][65];
  int b = blockIdx.y;
  int s0 = blockIdx.x * 64;
  int tid = threadIdx.x;
  int r = tid >> 2;
  int c0 = (tid & 3) << 4;
  for (int d0 = 0; d0 < 768; d0 += 64) {
    const float* fp = feats + ((size_t)b*768 + d0 + r)*1024 + s0 + c0;
#pragma unroll
    for (int i = 0; i < 16; ++i) T[r][c0 + i] = fp[i];
    __syncthreads();
    float* xp = x + ((size_t)(b*SEQ0 + s0 + r))*768 + d0 + c0;
    const float* pp = pe + (size_t)(s0 + r)*768 + d0 + c0;
#pragma unroll
    for (int i = 0; i < 16; ++i) xp[i] = T[c0 + i][r] + pp[i];
    __syncthreads();
  }
}

__global__ __launch_bounds__(256) void build_misc_kernel(
    const float* __restrict__ past, const int* __restrict__ intent,
    const float* __restrict__ int_emb, const float* __restrict__ past_W,
    const float* __restrict__ past_b, const float* __restrict__ te,
    float* __restrict__ x)
{
  int b = blockIdx.y;
  int i = blockIdx.x;  // 0..16
  int tid = threadIdx.x;
  if (i == 0) {
    int idx = intent[b] - 1;
    idx = max(0, min(2, idx));
    for (int d = tid; d < 768; d += 256)
      x[((size_t)(b*SEQ0 + 1024))*768 + d] = int_emb[idx*768 + d];
  } else {
    int pi = i - 1;
    float p0 = past[(b*NPAST + pi)*6 + 0], p1 = past[(b*NPAST + pi)*6 + 1];
    float p2 = past[(b*NPAST + pi)*6 + 2], p3 = past[(b*NPAST + pi)*6 + 3];
    float p4 = past[(b*NPAST + pi)*6 + 4], p5 = past[(b*NPAST + pi)*6 + 5];
    for (int d = tid; d < 768; d += 256) {
      float s = past_b[d] + te[(size_t)pi*768 + d];
      s += p0*past_W[0*768 + d] + p1*past_W[1*768 + d] + p2*past_W[2*768 + d];
      s += p3*past_W[3*768 + d] + p4*past_W[4*768 + d] + p5*past_W[5*768 + d];
      x[((size_t)(b*SEQ0 + 1025 + pi))*768 + d] = s;
    }
  }
}

// ---------------- layernorm (prefill) ----------------
__global__ __launch_bounds__(256) void ln_kernel(
    const float* __restrict__ x, const float* __restrict__ g,
    const float* __restrict__ bta, float* __restrict__ h)
{
  __shared__ float red[4];
  size_t row = blockIdx.x;
  const float* xr = x + row*768;
  float* hr = h + row*768;
  int tid = threadIdx.x;
  float v0 = xr[tid], v1 = xr[tid+256], v2 = xr[tid+512];
  float m = block_sum256(v0+v1+v2, red) * (1.f/768.f);
  float d0 = v0-m, d1 = v1-m, d2 = v2-m;
  float var = block_sum256(d0*d0 + d1*d1 + d2*d2, red) * (1.f/768.f);
  float inv = rsqrtf(var + 1e-5f);
  hr[tid]     = d0*inv*g[tid]     + bta[tid];
  hr[tid+256] = d1*inv*g[tid+256] + bta[tid+256];
  hr[tid+512] = d2*inv*g[tid+512] + bta[tid+512];
}

// ---------------- tiled fp32 GEMM: C(M,N) = A(M,K) @ W(K,N) + bias ----------------
// mode: 0 store, 1 relu, 2 add-into-C
__global__ __launch_bounds__(256) void gemm_f32_kernel(
    const float* __restrict__ A, const float* __restrict__ W,
    const float* __restrict__ bias, float* __restrict__ C,
    int M, int N, int K, int mode)
{
  __shared__ float As[16][132];
  __shared__ float Bs[16][68];
  int tid = threadIdx.x;
  int n0 = blockIdx.x * 64;
  int m0 = blockIdx.y * 128;
  int ty = tid >> 4, tx = tid & 15;
  int arow = tid >> 2, ac0 = (tid & 3) << 2;
  int brow = tid >> 4, bc0 = (tid & 15) << 2;
  float acc[8][4] = {};
  for (int k0 = 0; k0 < K; k0 += 16) {
#pragma unroll
    for (int half = 0; half < 2; ++half) {
      int m = m0 + arow + half*64;
      float4 av = make_float4(0.f, 0.f, 0.f, 0.f);
      if (m < M) av = *(const float4*)(A + (size_t)m*K + k0 + ac0);
      As[ac0+0][arow + half*64] = av.x;
      As[ac0+1][arow + half*64] = av.y;
      As[ac0+2][arow + half*64] = av.z;
      As[ac0+3][arow + half*64] = av.w;
    }
    float4 wv = *(const float4*)(W + (size_t)(k0 + brow)*N + n0 + bc0);
    Bs[brow][bc0+0] = wv.x; Bs[brow][bc0+1] = wv.y;
    Bs[brow][bc0+2] = wv.z; Bs[brow][bc0+3] = wv.w;
    __syncthreads();
#pragma unroll
    for (int kk = 0; kk < 16; ++kk) {
      const float4* ap = (const float4*)&As[kk][ty*8];
      float4 a04 = ap[0], a14 = ap[1];
      float4 b4 = *(const float4*)&Bs[kk][tx*4];
      float a[8] = {a04.x, a04.y, a04.z, a04.w, a14.x, a14.y, a14.z, a14.w};
      float bv[4] = {b4.x, b4.y, b4.z, b4.w};
#pragma unroll
      for (int i = 0; i < 8; ++i)
#pragma unroll
        for (int j = 0; j < 4; ++j)
          acc[i][j] += a[i]*bv[j];
    }
    __syncthreads();
  }
  float4 bias4 = *(const float4*)(bias + n0 + tx*4);
#pragma unroll
  for (int i = 0; i < 8; ++i) {
    int m = m0 + ty*8 + i;
    if (m >= M) break;
    float4 r;
    r.x = acc[i][0] + bias4.x; r.y = acc[i][1] + bias4.y;
    r.z = acc[i][2] + bias4.z; r.w = acc[i][3] + bias4.w;
    if (mode == 1) {
      r.x = fmaxf(r.x, 0.f); r.y = fmaxf(r.y, 0.f);
      r.z = fmaxf(r.z, 0.f); r.w = fmaxf(r.w, 0.f);
    }
    float* cp = C + (size_t)m*N + n0 + tx*4;
    if (mode == 2) {
      float4 o = *(const float4*)cp;
      r.x += o.x; r.y += o.y; r.z += o.z; r.w += o.w;
    }
    *(float4*)cp = r;
  }
}

// ---------------- scatter K/V into cache (prefill) ----------------
__global__ __launch_bounds__(256) void scatter_kv_kernel(
    const float* __restrict__ qkv, float* __restrict__ kc, float* __restrict__ vc,
    int S, int spad)
{
  int s = blockIdx.x, b = blockIdx.y;
  const float* row = qkv + ((size_t)b*S + s)*2304;
  int tid = threadIdx.x;
#pragma unroll
  for (int i = 0; i < 3; ++i) {
    int j = tid + i*256;
    int hh = j / 48, hd = j - hh*48;
    size_t dst = ((size_t)(b*16 + hh)*spad + s)*48 + hd;
    kc[dst] = row[768 + j];
    vc[dst] = row[1536 + j];
  }
}

// ---------------- causal flash attention (prefill), 32-row Q tiles ----------------
__global__ __launch_bounds__(256) void attn_prefill_kernel(
    const float* __restrict__ qkv, const float* __restrict__ Kc,
    const float* __restrict__ Vc, float* __restrict__ ctx, int S, int spad)
{
  __shared__ float Qs[32][49];
  __shared__ float Ks[64][49];
  __shared__ float Vs[64][49];
  __shared__ float Ps[32][65];
  __shared__ float mrow[32], lrow[32], resc[32];
  int tid = threadIdx.x;
  int qt = blockIdx.x, h = blockIdx.y, b = blockIdx.z;
  int q0 = qt * 32;
  for (int i = tid; i < 32*48; i += 256) {
    int r = i / 48, d = i - r*48;
    int s = q0 + r;
    Qs[r][d] = (s < S) ? qkv[((size_t)(b*S + s))*2304 + h*48 + d] * SCALE_QK : 0.f;
  }
  if (tid < 32) { mrow[tid] = -INFINITY; lrow[tid] = 0.f; }
  float acc[2][3] = {};
  int pr0 = (tid >> 4) << 1;   // PV rows
  int pc  = tid & 15;          // col group (3 cols)
  int sr  = tid & 31;          // score row
  int skg = tid >> 5;          // score key group
  int q_last = min(q0 + 31, S - 1);
  const float* Kb = Kc + (size_t)(b*16 + h)*spad*48;
  const float* Vb = Vc + (size_t)(b*16 + h)*spad*48;
  __syncthreads();
  // hoist this thread's Q row into registers (fixed across chunks)
  float qreg[48];
#pragma unroll
  for (int d = 0; d < 48; ++d) qreg[d] = Qs[sr][d];
  for (int k0 = 0; k0 <= q_last; k0 += 64) {
    int kn = min(64, q_last - k0 + 1);
    for (int i = tid; i < 64*48; i += 256) {
      int r = i / 48, d = i - r*48;
      bool ok = r < kn;
      Ks[r][d] = ok ? Kb[(size_t)(k0 + r)*48 + d] : 0.f;
      Vs[r][d] = ok ? Vb[(size_t)(k0 + r)*48 + d] : 0.f;
    }
    __syncthreads();
    {
      int qg = q0 + sr;
#pragma unroll
      for (int jj = 0; jj < 8; ++jj) {
        int k = skg*8 + jj;
        float s = 0.f;
#pragma unroll
        for (int d = 0; d < 48; ++d) s += qreg[d] * Ks[k][d];
        int kg = k0 + k;
        bool valid = (qg < S) && (k < kn) && (kg <= qg);
        Ps[sr][k] = valid ? s : -INFINITY;
      }
    }
    __syncthreads();
    if (tid < 32) {
      int r = tid;
      float mold = mrow[r];
      float mx = mold;
#pragma unroll 8
      for (int k = 0; k < 64; ++k) mx = fmaxf(mx, Ps[r][k]);
      float rs = 1.f;
      if (mx > -INFINITY) {
        rs = (mold > -INFINITY) ? __expf(mold - mx) : 0.f;
        float psum = 0.f;
#pragma unroll 8
        for (int k = 0; k < 64; ++k) {
          float p = __expf(Ps[r][k] - mx);
          Ps[r][k] = p;
          psum += p;
        }
        lrow[r] = lrow[r]*rs + psum;
        mrow[r] = mx;
      } else {
#pragma unroll 8
        for (int k = 0; k < 64; ++k) Ps[r][k] = 0.f;
        rs = 1.f;
      }
      resc[r] = rs;
    }
    __syncthreads();
#pragma unroll
    for (int rr = 0; rr < 2; ++rr) {
      int r = pr0 + rr;
      float f = resc[r];
      float a0 = acc[rr][0]*f, a1 = acc[rr][1]*f, a2 = acc[rr][2]*f;
#pragma unroll 16
      for (int k = 0; k < 64; ++k) {
        float p = Ps[r][k];
        a0 += p * Vs[k][pc*3+0];
        a1 += p * Vs[k][pc*3+1];
        a2 += p * Vs[k][pc*3+2];
      }
      acc[rr][0] = a0; acc[rr][1] = a1; acc[rr][2] = a2;
    }
    __syncthreads();
  }
#pragma unroll
  for (int rr = 0; rr < 2; ++rr) {
    int r = pr0 + rr, s = q0 + r;
    if (s < S) {
      float invl = 1.f / lrow[r];
      float* cp = &ctx[((size_t)(b*S + s))*768 + h*48 + pc*3];
      cp[0] = acc[rr][0]*invl; cp[1] = acc[rr][1]*invl; cp[2] = acc[rr][2]*invl;
    }
  }
}

// ---------------- decode GEMV (optional fused LN on 768-row input) ----------------
// mode: 0 store, 1 relu, 2 add, 3 gelu
__global__ __launch_bounds__(256) void dec_gemv_kernel(
    const float* __restrict__ xin, size_t in_stride,
    const float* __restrict__ W, const float* __restrict__ bias,
    const float* __restrict__ ln_g, const float* __restrict__ ln_b,
    float* __restrict__ out, int K, int N, int mode,
    float* __restrict__ kc, float* __restrict__ vc, int pos, int spad)
{
  __shared__ float hs[3072];
  __shared__ float red[4];
  int tid = threadIdx.x;
  int b = blockIdx.y;
  const float* xr = xin + (size_t)b * in_stride;
  if (ln_g) {  // K must be 768
    float v0 = xr[tid], v1 = xr[tid+256], v2 = xr[tid+512];
    float m = block_sum256(v0+v1+v2, red) * (1.f/768.f);
    float d0 = v0-m, d1 = v1-m, d2 = v2-m;
    float var = block_sum256(d0*d0 + d1*d1 + d2*d2, red) * (1.f/768.f);
    float inv = rsqrtf(var + 1e-5f);
    hs[tid]     = d0*inv*ln_g[tid]     + ln_b[tid];
    hs[tid+256] = d1*inv*ln_g[tid+256] + ln_b[tid+256];
    hs[tid+512] = d2*inv*ln_g[tid+512] + ln_b[tid+512];
  } else {
    for (int k = tid; k < K; k += 256) hs[k] = xr[k];
  }
  __syncthreads();
  int n = blockIdx.x * 256 + tid;
  float acc = bias[n];
  const float* wp = W + n;
  for (int k = 0; k < K; k += 4) {
    acc += hs[k+0] * wp[(size_t)(k+0)*N];
    acc += hs[k+1] * wp[(size_t)(k+1)*N];
    acc += hs[k+2] * wp[(size_t)(k+2)*N];
    acc += hs[k+3] * wp[(size_t)(k+3)*N];
  }
  float v = acc;
  if (mode == 1) v = fmaxf(v, 0.f);
  else if (mode == 3) v = 0.5f*v*(1.f + erff(v*0.70710678118654752f));
  if (mode == 2) out[(size_t)b*N + n] += v;
  else out[(size_t)b*N + n] = v;
  if (kc) {
    if (n >= 768 && n < 1536) {
      int j = n - 768;
      kc[((size_t)(b*16 + j/48)*spad + pos)*48 + (j % 48)] = v;
    } else if (n >= 1536) {
      int j = n - 1536;
      vc[((size_t)(b*16 + j/48)*spad + pos)*48 + (j % 48)] = v;
    }
  }
}

// ---------------- decode attention (single new token) ----------------
__global__ __launch_bounds__(256) void dec_attn_kernel(
    const float* __restrict__ qkv_tok, const float* __restrict__ Kc,
    const float* __restrict__ Vc, float* __restrict__ ctx_tok, int S, int spad)
{
  __shared__ float qs[48];
  __shared__ float redm[4];
  __shared__ float reds[4];
  __shared__ float aw[4][48];
  int tid = threadIdx.x;
  int h = blockIdx.x, b = blockIdx.y;
  if (tid < 48) qs[tid] = qkv_tok[b*2304 + h*48 + tid] * SCALE_QK;
  __syncthreads();
  const float* Kb = Kc + (size_t)(b*16 + h)*spad*48;
  const float* Vb = Vc + (size_t)(b*16 + h)*spad*48;
  float ls[5];
  int cnt = 0;
  float lmax = -INFINITY;
  for (int k = tid; k < S; k += 256) {
    const float4* kr = (const float4*)(Kb + (size_t)k*48);
    float s = 0.f;
#pragma unroll
    for (int i = 0; i < 12; ++i) {
      float4 kv = kr[i];
      s += qs[4*i+0]*kv.x + qs[4*i+1]*kv.y + qs[4*i+2]*kv.z + qs[4*i+3]*kv.w;
    }
    ls[cnt++] = s;
    lmax = fmaxf(lmax, s);
  }
#pragma unroll
  for (int off = 32; off; off >>= 1) lmax = fmaxf(lmax, __shfl_down(lmax, off));
  if ((tid & 63) == 0) redm[tid >> 6] = lmax;
  __syncthreads();
  float M = fmaxf(fmaxf(redm[0], redm[1]), fmaxf(redm[2], redm[3]));
  float lsum = 0.f;
  float4 a[12];
#pragma unroll
  for (int i = 0; i < 12; ++i) a[i] = make_float4(0.f, 0.f, 0.f, 0.f);
  cnt = 0;
  for (int k = tid; k < S; k += 256) {
    float p = __expf(ls[cnt++] - M);
    lsum += p;
    const float4* vr = (const float4*)(Vb + (size_t)k*48);
#pragma unroll
    for (int i = 0; i < 12; ++i) {
      float4 vv = vr[i];
      a[i].x += p*vv.x; a[i].y += p*vv.y; a[i].z += p*vv.z; a[i].w += p*vv.w;
    }
  }
  float tot = block_sum256(lsum, reds);
#pragma unroll
  for (int i = 0; i < 12; ++i) {
    float x0 = a[i].x, x1 = a[i].y, x2 = a[i].z, x3 = a[i].w;
#pragma unroll
    for (int off = 32; off; off >>= 1) {
      x0 += __shfl_down(x0, off); x1 += __shfl_down(x1, off);
      x2 += __shfl_down(x2, off); x3 += __shfl_down(x3, off);
    }
    if ((tid & 63) == 0) {
      int w = tid >> 6;
      aw[w][4*i+0] = x0; aw[w][4*i+1] = x1; aw[w][4*i+2] = x2; aw[w][4*i+3] = x3;
    }
  }
  __syncthreads();
  if (tid < 48) {
    float s = aw[0][tid] + aw[1][tid] + aw[2][tid] + aw[3][tid];
    ctx_tok[b*768 + h*48 + tid] = s / tot;
  }
}

// ---------------- head stage 2: p = hdec @ dec2 + b ; write pred ; next token ----------------
__global__ __launch_bounds__(256) void head2_kernel(
    const float* __restrict__ hdec, const float* __restrict__ dec2_W,
    const float* __restrict__ dec2_b, const float* __restrict__ pos_W,
    const float* __restrict__ pos_b, const float* __restrict__ te,
    int t, float* __restrict__ outp, float* __restrict__ x_tok, int write_next)
{
  __shared__ float ps[2][2];
  int tid = threadIdx.x;
  int w = tid >> 6, lane = tid & 63;
  int b = w >> 1, j = w & 1;
  float partial = 0.f;
  for (int k = lane; k < 768; k += 64) partial += hdec[b*768 + k] * dec2_W[k*2 + j];
#pragma unroll
  for (int off = 32; off; off >>= 1) partial += __shfl_down(partial, off);
  if (lane == 0) {
    float v = partial + dec2_b[j];
    ps[b][j] = v;
    outp[(b*TDEC + t)*2 + j] = v;
  }
  __syncthreads();
  if (write_next) {
    for (int i = tid; i < 2*768; i += 256) {
      int b2 = i / 768, d = i - b2*768;
      x_tok[i] = ps[b2][0]*pos_W[d] + ps[b2][1]*pos_W[768 + d]
               + pos_b[d] + te[(size_t)(NPAST + t)*768 + d];
    }
  }
}

// ---------------- host ----------------
extern "C" void kernel_launch(void* const* d_in, const int* in_sizes, int n_in,
                              void* d_out, int out_size, void* d_ws, size_t ws_size,
                              hipStream_t stream) {
  (void)in_sizes; (void)n_in; (void)out_size; (void)ws_size;
  const float* feats   = (const float*)d_in[0];
  const float* past    = (const float*)d_in[1];
  const int*   intent  = (const int*)d_in[2];
  const float* img_pos = (const float*)d_in[3];
  const float* time_e  = (const float*)d_in[4];
  const float* int_emb = (const float*)d_in[5];
  const float* past_W  = (const float*)d_in[6];
  const float* past_b  = (const float*)d_in[7];
  const float* pos_W   = (const float*)d_in[8];
  const float* pos_b   = (const float*)d_in[9];
  const float* ln1_g   = (const float*)d_in[10];
  const float* ln1_b   = (const float*)d_in[11];
  const float* qkv_W   = (const float*)d_in[12];
  const float* qkv_b   = (const float*)d_in[13];
  const float* out_W   = (const float*)d_in[14];
  const float* out_b   = (const float*)d_in[15];
  const float* ln2_g   = (const float*)d_in[16];
  const float* ln2_b   = (const float*)d_in[17];
  const float* ff1_W   = (const float*)d_in[18];
  const float* ff1_b   = (const float*)d_in[19];
  const float* ff2_W   = (const float*)d_in[20];
  const float* ff2_b   = (const float*)d_in[21];
  const float* dec1_W  = (const float*)d_in[22];
  const float* dec1_b  = (const float*)d_in[23];
  const float* dec2_W  = (const float*)d_in[24];
  const float* dec2_b  = (const float*)d_in[25];
  float* outp = (float*)d_out;

  float* ws = (float*)d_ws;
  size_t off = 0;
  float* xbuf = ws + off;   off += (size_t)MM*DD;
  float* hbuf = ws + off;   off += (size_t)MM*DD;
  float* ctxbuf = hbuf;  // alias: h consumed before attention writes ctx
  float* bigbuf = ws + off; off += (size_t)MM*3072;
  float* Kc = ws + off;     off += (size_t)LL*BB*HH*SPAD*HDIM;
  float* Vc = ws + off;     off += (size_t)LL*BB*HH*SPAD*HDIM;
  float* x_tok = ws + off;  off += BB*DD;
  float* hdec = ws + off;   off += BB*DD;
  float* qkv_tok = ws + off; off += BB*2304;
  float* ctx_tok = ws + off; off += BB*DD;
  float* ff_tok = ws + off;  off += BB*3072;

  const size_t KVL = (size_t)BB*HH*SPAD*HDIM;  // per-layer cache stride

  // ---- build initial sequence ----
  build_img_kernel<<<dim3(NIMG/64, BB), 256, 0, stream>>>(feats, img_pos, xbuf);
  build_misc_kernel<<<dim3(17, BB), 256, 0, stream>>>(past, intent, int_emb, past_W, past_b, time_e, xbuf);

  // ---- prefill: 3 encoder layers over S0=1041 ----
  const int mtiles = (MM + 127) / 128;  // 17
  for (int l = 0; l < LL; ++l) {
    float* kcl = Kc + (size_t)l*KVL;
    float* vcl = Vc + (size_t)l*KVL;
    ln_kernel<<<MM, 256, 0, stream>>>(xbuf, ln1_g + l*DD, ln1_b + l*DD, hbuf);
    gemm_f32_kernel<<<dim3(2304/64, mtiles), 256, 0, stream>>>(
        hbuf, qkv_W + (size_t)l*DD*2304, qkv_b + l*2304, bigbuf, MM, 2304, DD, 0);
    scatter_kv_kernel<<<dim3(SEQ0, BB), 256, 0, stream>>>(bigbuf, kcl, vcl, SEQ0, SPAD);
    attn_prefill_kernel<<<dim3((SEQ0 + 31)/32, HH, BB), 256, 0, stream>>>(
        bigbuf, kcl, vcl, ctxbuf, SEQ0, SPAD);
    gemm_f32_kernel<<<dim3(DD/64, mtiles), 256, 0, stream>>>(
        ctxbuf, out_W + (size_t)l*DD*DD, out_b + l*DD, xbuf, MM, DD, DD, 2);
    ln_kernel<<<MM, 256, 0, stream>>>(xbuf, ln2_g + l*DD, ln2_b + l*DD, hbuf);
    gemm_f32_kernel<<<dim3(3072/64, mtiles), 256, 0, stream>>>(
        hbuf, ff1_W + (size_t)l*DD*3072, ff1_b + l*3072, bigbuf, MM, 3072, DD, 1);
    gemm_f32_kernel<<<dim3(DD/64, mtiles), 256, 0, stream>>>(
        bigbuf, ff2_W + (size_t)l*3072*DD, ff2_b + l*DD, xbuf, MM, DD, 3072, 2);
  }

  // ---- head for t=0 (last prefill token, row 1040 of each batch) ----
  dec_gemv_kernel<<<dim3(DD/256, BB), 256, 0, stream>>>(
      xbuf + (size_t)(SEQ0 - 1)*DD, (size_t)SEQ0*DD, dec1_W, dec1_b,
      nullptr, nullptr, hdec, DD, DD, 3, nullptr, nullptr, 0, 0);
  head2_kernel<<<1, 256, 0, stream>>>(hdec, dec2_W, dec2_b, pos_W, pos_b, time_e,
                                      0, outp, x_tok, 1);

  // ---- incremental decode steps t = 1..19 ----
  for (int t = 1; t < TDEC; ++t) {
    int S = SEQ0 + t;
    int pos = S - 1;
    for (int l = 0; l < LL; ++l) {
      float* kcl = Kc + (size_t)l*KVL;
      float* vcl = Vc + (size_t)l*KVL;
      dec_gemv_kernel<<<dim3(2304/256, BB), 256, 0, stream>>>(
          x_tok, (size_t)DD, qkv_W + (size_t)l*DD*2304, qkv_b + l*2304,
          ln1_g + l*DD, ln1_b + l*DD, qkv_tok, DD, 2304, 0, kcl, vcl, pos, SPAD);
      dec_attn_kernel<<<dim3(HH, BB), 256, 0, stream>>>(qkv_tok, kcl, vcl, ctx_tok, S, SPAD);
      dec_gemv_kernel<<<dim3(DD/256, BB), 256, 0, stream>>>(
          ctx_tok, (size_t)DD, out_W + (size_t)l*DD*DD, out_b + l*DD,
          nullptr, nullptr, x_tok, DD, DD, 2, nullptr, nullptr, 0, 0);
      dec_gemv_kernel<<<dim3(3072/256, BB), 256, 0, stream>>>(
          x_tok, (size_t)DD, ff1_W + (size_t)l*DD*3072, ff1_b + l*3072,
          ln2_g + l*DD, ln2_b + l*DD, ff_tok, DD, 3072, 1, nullptr, nullptr, 0, 0);
      dec_gemv_kernel<<<dim3(DD/256, BB), 256, 0, stream>>>(
          ff_tok, (size_t)3072, ff2_W + (size_t)l*3072*DD, ff2_b + l*DD,
          nullptr, nullptr, x_tok, 3072, DD, 2, nullptr, nullptr, 0, 0);
    }
    dec_gemv_kernel<<<dim3(DD/256, BB), 256, 0, stream>>>(
        x_tok, (size_t)DD, dec1_W, dec1_b, nullptr, nullptr,
        hdec, DD, DD, 3, nullptr, nullptr, 0, 0);
    head2_kernel<<<1, 256, 0, stream>>>(hdec, dec2_W, dec2_b, pos_W, pos_b, time_e,
                                        t, outp, x_tok, (t < TDEC - 1) ? 1 : 0);
  }
}

// Round 2
// 8539.535 us; speedup vs baseline: 2.3093x; 2.3093x over previous
//
#include <hip/hip_runtime.h>
#include <math.h>

#define BB 2
#define DD 768
#define HH 16
#define HDIM 48
#define LL 3
#define NIMG 1024
#define NPAST 16
#define TDEC 20
#define SEQ0 1041
#define SPAD 1064
#define MM (BB*SEQ0)
#define SCALE_QK 0.14433756729740643f

// ---------------- utils ----------------
__device__ __forceinline__ float block_sum256(float v, float* red) {
#pragma unroll
  for (int off = 32; off; off >>= 1) v += __shfl_down(v, off);
  __syncthreads();
  if ((threadIdx.x & 63) == 0) red[threadIdx.x >> 6] = v;
  __syncthreads();
  return red[0] + red[1] + red[2] + red[3];
}

// ---------------- build sequence ----------------
__global__ __launch_bounds__(256) void build_img_kernel(
    const float* __restrict__ feats, const float* __restrict__ pe, float* __restrict__ x)
{
  __shared__ float T[64][65];
  int b = blockIdx.y;
  int s0 = blockIdx.x * 64;
  int tid = threadIdx.x;
  int r = tid >> 2;
  int c0 = (tid & 3) << 4;
  for (int d0 = 0; d0 < 768; d0 += 64) {
    const float* fp = feats + ((size_t)b*768 + d0 + r)*1024 + s0 + c0;
#pragma unroll
    for (int i = 0; i < 16; ++i) T[r][c0 + i] = fp[i];
    __syncthreads();
    float* xp = x + ((size_t)(b*SEQ0 + s0 + r))*768 + d0 + c0;
    const float* pp = pe + (size_t)(s0 + r)*768 + d0 + c0;
#pragma unroll
    for (int i = 0; i < 16; ++i) xp[i] = T[c0 + i][r] + pp[i];
    __syncthreads();
  }
}

__global__ __launch_bounds__(256) void build_misc_kernel(
    const float* __restrict__ past, const int* __restrict__ intent,
    const float* __restrict__ int_emb, const float* __restrict__ past_W,
    const float* __restrict__ past_b, const float* __restrict__ te,
    float* __restrict__ x)
{
  int b = blockIdx.y;
  int i = blockIdx.x;  // 0..16
  int tid = threadIdx.x;
  if (i == 0) {
    int idx = intent[b] - 1;
    idx = max(0, min(2, idx));
    for (int d = tid; d < 768; d += 256)
      x[((size_t)(b*SEQ0 + 1024))*768 + d] = int_emb[idx*768 + d];
  } else {
    int pi = i - 1;
    float p0 = past[(b*NPAST + pi)*6 + 0], p1 = past[(b*NPAST + pi)*6 + 1];
    float p2 = past[(b*NPAST + pi)*6 + 2], p3 = past[(b*NPAST + pi)*6 + 3];
    float p4 = past[(b*NPAST + pi)*6 + 4], p5 = past[(b*NPAST + pi)*6 + 5];
    for (int d = tid; d < 768; d += 256) {
      float s = past_b[d] + te[(size_t)pi*768 + d];
      s += p0*past_W[0*768 + d] + p1*past_W[1*768 + d] + p2*past_W[2*768 + d];
      s += p3*past_W[3*768 + d] + p4*past_W[4*768 + d] + p5*past_W[5*768 + d];
      x[((size_t)(b*SEQ0 + 1025 + pi))*768 + d] = s;
    }
  }
}

// ---------------- layernorm (prefill) ----------------
__global__ __launch_bounds__(256) void ln_kernel(
    const float* __restrict__ x, const float* __restrict__ g,
    const float* __restrict__ bta, float* __restrict__ h)
{
  __shared__ float red[4];
  size_t row = blockIdx.x;
  const float* xr = x + row*768;
  float* hr = h + row*768;
  int tid = threadIdx.x;
  float v0 = xr[tid], v1 = xr[tid+256], v2 = xr[tid+512];
  float m = block_sum256(v0+v1+v2, red) * (1.f/768.f);
  float d0 = v0-m, d1 = v1-m, d2 = v2-m;
  float var = block_sum256(d0*d0 + d1*d1 + d2*d2, red) * (1.f/768.f);
  float inv = rsqrtf(var + 1e-5f);
  hr[tid]     = d0*inv*g[tid]     + bta[tid];
  hr[tid+256] = d1*inv*g[tid+256] + bta[tid+256];
  hr[tid+512] = d2*inv*g[tid+512] + bta[tid+512];
}

// ---------------- tiled fp32 GEMM: C(M,N) = A(M,K) @ W(K,N) + bias ----------------
// mode: 0 store, 1 relu, 2 add-into-C
__global__ __launch_bounds__(256) void gemm_f32_kernel(
    const float* __restrict__ A, const float* __restrict__ W,
    const float* __restrict__ bias, float* __restrict__ C,
    int M, int N, int K, int mode)
{
  __shared__ float As[16][132];
  __shared__ float Bs[16][68];
  int tid = threadIdx.x;
  int n0 = blockIdx.x * 64;
  int m0 = blockIdx.y * 128;
  int ty = tid >> 4, tx = tid & 15;
  int arow = tid >> 2, ac0 = (tid & 3) << 2;
  int brow = tid >> 4, bc0 = (tid & 15) << 2;
  float acc[8][4] = {};
  for (int k0 = 0; k0 < K; k0 += 16) {
#pragma unroll
    for (int half = 0; half < 2; ++half) {
      int m = m0 + arow + half*64;
      float4 av = make_float4(0.f, 0.f, 0.f, 0.f);
      if (m < M) av = *(const float4*)(A + (size_t)m*K + k0 + ac0);
      As[ac0+0][arow + half*64] = av.x;
      As[ac0+1][arow + half*64] = av.y;
      As[ac0+2][arow + half*64] = av.z;
      As[ac0+3][arow + half*64] = av.w;
    }
    float4 wv = *(const float4*)(W + (size_t)(k0 + brow)*N + n0 + bc0);
    Bs[brow][bc0+0] = wv.x; Bs[brow][bc0+1] = wv.y;
    Bs[brow][bc0+2] = wv.z; Bs[brow][bc0+3] = wv.w;
    __syncthreads();
#pragma unroll
    for (int kk = 0; kk < 16; ++kk) {
      const float4* ap = (const float4*)&As[kk][ty*8];
      float4 a04 = ap[0], a14 = ap[1];
      float4 b4 = *(const float4*)&Bs[kk][tx*4];
      float a[8] = {a04.x, a04.y, a04.z, a04.w, a14.x, a14.y, a14.z, a14.w};
      float bv[4] = {b4.x, b4.y, b4.z, b4.w};
#pragma unroll
      for (int i = 0; i < 8; ++i)
#pragma unroll
        for (int j = 0; j < 4; ++j)
          acc[i][j] += a[i]*bv[j];
    }
    __syncthreads();
  }
  float4 bias4 = *(const float4*)(bias + n0 + tx*4);
#pragma unroll
  for (int i = 0; i < 8; ++i) {
    int m = m0 + ty*8 + i;
    if (m >= M) break;
    float4 r;
    r.x = acc[i][0] + bias4.x; r.y = acc[i][1] + bias4.y;
    r.z = acc[i][2] + bias4.z; r.w = acc[i][3] + bias4.w;
    if (mode == 1) {
      r.x = fmaxf(r.x, 0.f); r.y = fmaxf(r.y, 0.f);
      r.z = fmaxf(r.z, 0.f); r.w = fmaxf(r.w, 0.f);
    }
    float* cp = C + (size_t)m*N + n0 + tx*4;
    if (mode == 2) {
      float4 o = *(const float4*)cp;
      r.x += o.x; r.y += o.y; r.z += o.z; r.w += o.w;
    }
    *(float4*)cp = r;
  }
}

// ---------------- scatter K/V into cache (prefill) ----------------
__global__ __launch_bounds__(256) void scatter_kv_kernel(
    const float* __restrict__ qkv, float* __restrict__ kc, float* __restrict__ vc,
    int S, int spad)
{
  int s = blockIdx.x, b = blockIdx.y;
  const float* row = qkv + ((size_t)b*S + s)*2304;
  int tid = threadIdx.x;
#pragma unroll
  for (int i = 0; i < 3; ++i) {
    int j = tid + i*256;
    int hh = j / 48, hd = j - hh*48;
    size_t dst = ((size_t)(b*16 + hh)*spad + s)*48 + hd;
    kc[dst] = row[768 + j];
    vc[dst] = row[1536 + j];
  }
}

// ---------------- causal flash attention (prefill), 32-row Q tiles ----------------
__global__ __launch_bounds__(256) void attn_prefill_kernel(
    const float* __restrict__ qkv, const float* __restrict__ Kc,
    const float* __restrict__ Vc, float* __restrict__ ctx, int S, int spad)
{
  __shared__ float Qs[32][49];
  __shared__ float Ks[64][49];
  __shared__ float Vs[64][49];
  __shared__ float Ps[32][65];
  __shared__ float mrow[32], lrow[32], resc[32];
  int tid = threadIdx.x;
  int qt = blockIdx.x, h = blockIdx.y, b = blockIdx.z;
  int q0 = qt * 32;
  for (int i = tid; i < 32*48; i += 256) {
    int r = i / 48, d = i - r*48;
    int s = q0 + r;
    Qs[r][d] = (s < S) ? qkv[((size_t)(b*S + s))*2304 + h*48 + d] * SCALE_QK : 0.f;
  }
  if (tid < 32) { mrow[tid] = -INFINITY; lrow[tid] = 0.f; }
  float acc[2][3] = {};
  int pr0 = (tid >> 4) << 1;   // PV rows
  int pc  = tid & 15;          // col group (3 cols)
  int sr  = tid & 31;          // score row
  int skg = tid >> 5;          // score key group
  int q_last = min(q0 + 31, S - 1);
  const float* Kb = Kc + (size_t)(b*16 + h)*spad*48;
  const float* Vb = Vc + (size_t)(b*16 + h)*spad*48;
  __syncthreads();
  float qreg[48];
#pragma unroll
  for (int d = 0; d < 48; ++d) qreg[d] = Qs[sr][d];
  for (int k0 = 0; k0 <= q_last; k0 += 64) {
    int kn = min(64, q_last - k0 + 1);
    for (int i = tid; i < 64*48; i += 256) {
      int r = i / 48, d = i - r*48;
      bool ok = r < kn;
      Ks[r][d] = ok ? Kb[(size_t)(k0 + r)*48 + d] : 0.f;
      Vs[r][d] = ok ? Vb[(size_t)(k0 + r)*48 + d] : 0.f;
    }
    __syncthreads();
    {
      int qg = q0 + sr;
#pragma unroll
      for (int jj = 0; jj < 8; ++jj) {
        int k = skg*8 + jj;
        float s = 0.f;
#pragma unroll
        for (int d = 0; d < 48; ++d) s += qreg[d] * Ks[k][d];
        int kg = k0 + k;
        bool valid = (qg < S) && (k < kn) && (kg <= qg);
        Ps[sr][k] = valid ? s : -INFINITY;
      }
    }
    __syncthreads();
    if (tid < 32) {
      int r = tid;
      float mold = mrow[r];
      float mx = mold;
#pragma unroll 8
      for (int k = 0; k < 64; ++k) mx = fmaxf(mx, Ps[r][k]);
      float rs = 1.f;
      if (mx > -INFINITY) {
        rs = (mold > -INFINITY) ? __expf(mold - mx) : 0.f;
        float psum = 0.f;
#pragma unroll 8
        for (int k = 0; k < 64; ++k) {
          float p = __expf(Ps[r][k] - mx);
          Ps[r][k] = p;
          psum += p;
        }
        lrow[r] = lrow[r]*rs + psum;
        mrow[r] = mx;
      } else {
#pragma unroll 8
        for (int k = 0; k < 64; ++k) Ps[r][k] = 0.f;
        rs = 1.f;
      }
      resc[r] = rs;
    }
    __syncthreads();
#pragma unroll
    for (int rr = 0; rr < 2; ++rr) {
      int r = pr0 + rr;
      float f = resc[r];
      float a0 = acc[rr][0]*f, a1 = acc[rr][1]*f, a2 = acc[rr][2]*f;
#pragma unroll 16
      for (int k = 0; k < 64; ++k) {
        float p = Ps[r][k];
        a0 += p * Vs[k][pc*3+0];
        a1 += p * Vs[k][pc*3+1];
        a2 += p * Vs[k][pc*3+2];
      }
      acc[rr][0] = a0; acc[rr][1] = a1; acc[rr][2] = a2;
    }
    __syncthreads();
  }
#pragma unroll
  for (int rr = 0; rr < 2; ++rr) {
    int r = pr0 + rr, s = q0 + r;
    if (s < S) {
      float invl = 1.f / lrow[r];
      float* cp = &ctx[((size_t)(b*S + s))*768 + h*48 + pc*3];
      cp[0] = acc[rr][0]*invl; cp[1] = acc[rr][1]*invl; cp[2] = acc[rr][2]*invl;
    }
  }
}

// ---------------- decode GEMV v2: B=2 fused, K-split within block ----------------
// NT threads = SEGS*64. Each block: 64 outputs (n0..n0+63) for BOTH batches.
// lane = tid&63 -> output; seg = tid>>6 -> K-segment. LDS partial reduce.
// mode: 0 store, 1 relu, 2 add-into-out, 3 gelu
template<int NT>
__global__ __launch_bounds__(NT) void dgemv_kernel(
    const float* __restrict__ xin, size_t in_stride,
    const float* __restrict__ W, const float* __restrict__ bias,
    const float* __restrict__ ln_g, const float* __restrict__ ln_b,
    float* __restrict__ out, int K, int N, int mode,
    float* __restrict__ kc, float* __restrict__ vc, int pos, int spad)
{
  constexpr int SEGS = NT / 64;
  __shared__ float hs[2][3072];
  __shared__ float part[8][2][64];
  __shared__ float red[4];
  int tid = threadIdx.x;
  if (NT == 256 && ln_g) {  // K == 768
#pragma unroll
    for (int b = 0; b < 2; ++b) {
      const float* xr = xin + (size_t)b * in_stride;
      float v0 = xr[tid], v1 = xr[tid+256], v2 = xr[tid+512];
      float m = block_sum256(v0+v1+v2, red) * (1.f/768.f);
      float d0 = v0-m, d1 = v1-m, d2 = v2-m;
      float var = block_sum256(d0*d0 + d1*d1 + d2*d2, red) * (1.f/768.f);
      float inv = rsqrtf(var + 1e-5f);
      hs[b][tid]     = d0*inv*ln_g[tid]     + ln_b[tid];
      hs[b][tid+256] = d1*inv*ln_g[tid+256] + ln_b[tid+256];
      hs[b][tid+512] = d2*inv*ln_g[tid+512] + ln_b[tid+512];
    }
  } else {
#pragma unroll
    for (int b = 0; b < 2; ++b) {
      const float* xr = xin + (size_t)b * in_stride;
      for (int k = tid; k < K; k += NT) hs[b][k] = xr[k];
    }
  }
  __syncthreads();
  int lane = tid & 63, seg = tid >> 6;
  int n = blockIdx.x * 64 + lane;
  int chunk = K / SEGS;
  int k0 = seg * chunk;
  const float* wp = W + n;
  float a0 = 0.f, a1 = 0.f;
  for (int k = k0; k < k0 + chunk; k += 8) {
#pragma unroll
    for (int u = 0; u < 8; ++u) {
      float w = wp[(size_t)(k+u)*N];
      a0 += hs[0][k+u] * w;
      a1 += hs[1][k+u] * w;
    }
  }
  part[seg][0][lane] = a0;
  part[seg][1][lane] = a1;
  __syncthreads();
  if (tid < 128) {
    int b = tid >> 6, l = tid & 63;
    int nn = blockIdx.x * 64 + l;
    float v = bias[nn];
#pragma unroll
    for (int s = 0; s < SEGS; ++s) v += part[s][b][l];
    if (mode == 1) v = fmaxf(v, 0.f);
    else if (mode == 3) v = 0.5f*v*(1.f + erff(v*0.70710678118654752f));
    if (mode == 2) out[(size_t)b*N + nn] += v;
    else out[(size_t)b*N + nn] = v;
    if (kc) {
      if (nn >= 768 && nn < 1536) {
        int j = nn - 768;
        kc[((size_t)(b*16 + j/48)*spad + pos)*48 + (j % 48)] = v;
      } else if (nn >= 1536) {
        int j = nn - 1536;
        vc[((size_t)(b*16 + j/48)*spad + pos)*48 + (j % 48)] = v;
      }
    }
  }
}

// ---------------- decode attention (single new token) ----------------
__global__ __launch_bounds__(256) void dec_attn_kernel(
    const float* __restrict__ qkv_tok, const float* __restrict__ Kc,
    const float* __restrict__ Vc, float* __restrict__ ctx_tok, int S, int spad)
{
  __shared__ float qs[48];
  __shared__ float redm[4];
  __shared__ float reds[4];
  __shared__ float aw[4][48];
  int tid = threadIdx.x;
  int h = blockIdx.x, b = blockIdx.y;
  if (tid < 48) qs[tid] = qkv_tok[b*2304 + h*48 + tid] * SCALE_QK;
  __syncthreads();
  const float* Kb = Kc + (size_t)(b*16 + h)*spad*48;
  const float* Vb = Vc + (size_t)(b*16 + h)*spad*48;
  float ls[5];
  int cnt = 0;
  float lmax = -INFINITY;
  for (int k = tid; k < S; k += 256) {
    const float4* kr = (const float4*)(Kb + (size_t)k*48);
    float s = 0.f;
#pragma unroll
    for (int i = 0; i < 12; ++i) {
      float4 kv = kr[i];
      s += qs[4*i+0]*kv.x + qs[4*i+1]*kv.y + qs[4*i+2]*kv.z + qs[4*i+3]*kv.w;
    }
    ls[cnt++] = s;
    lmax = fmaxf(lmax, s);
  }
#pragma unroll
  for (int off = 32; off; off >>= 1) lmax = fmaxf(lmax, __shfl_down(lmax, off));
  if ((tid & 63) == 0) redm[tid >> 6] = lmax;
  __syncthreads();
  float M = fmaxf(fmaxf(redm[0], redm[1]), fmaxf(redm[2], redm[3]));
  float lsum = 0.f;
  float4 a[12];
#pragma unroll
  for (int i = 0; i < 12; ++i) a[i] = make_float4(0.f, 0.f, 0.f, 0.f);
  cnt = 0;
  for (int k = tid; k < S; k += 256) {
    float p = __expf(ls[cnt++] - M);
    lsum += p;
    const float4* vr = (const float4*)(Vb + (size_t)k*48);
#pragma unroll
    for (int i = 0; i < 12; ++i) {
      float4 vv = vr[i];
      a[i].x += p*vv.x; a[i].y += p*vv.y; a[i].z += p*vv.z; a[i].w += p*vv.w;
    }
  }
  float tot = block_sum256(lsum, reds);
#pragma unroll
  for (int i = 0; i < 12; ++i) {
    float x0 = a[i].x, x1 = a[i].y, x2 = a[i].z, x3 = a[i].w;
#pragma unroll
    for (int off = 32; off; off >>= 1) {
      x0 += __shfl_down(x0, off); x1 += __shfl_down(x1, off);
      x2 += __shfl_down(x2, off); x3 += __shfl_down(x3, off);
    }
    if ((tid & 63) == 0) {
      int w = tid >> 6;
      aw[w][4*i+0] = x0; aw[w][4*i+1] = x1; aw[w][4*i+2] = x2; aw[w][4*i+3] = x3;
    }
  }
  __syncthreads();
  if (tid < 48) {
    float s = aw[0][tid] + aw[1][tid] + aw[2][tid] + aw[3][tid];
    ctx_tok[b*768 + h*48 + tid] = s / tot;
  }
}

// ---------------- head stage 2 ----------------
__global__ __launch_bounds__(256) void head2_kernel(
    const float* __restrict__ hdec, const float* __restrict__ dec2_W,
    const float* __restrict__ dec2_b, const float* __restrict__ pos_W,
    const float* __restrict__ pos_b, const float* __restrict__ te,
    int t, float* __restrict__ outp, float* __restrict__ x_tok, int write_next)
{
  __shared__ float ps[2][2];
  int tid = threadIdx.x;
  int w = tid >> 6, lane = tid & 63;
  int b = w >> 1, j = w & 1;
  float partial = 0.f;
  for (int k = lane; k < 768; k += 64) partial += hdec[b*768 + k] * dec2_W[k*2 + j];
#pragma unroll
  for (int off = 32; off; off >>= 1) partial += __shfl_down(partial, off);
  if (lane == 0) {
    float v = partial + dec2_b[j];
    ps[b][j] = v;
    outp[(b*TDEC + t)*2 + j] = v;
  }
  __syncthreads();
  if (write_next) {
    for (int i = tid; i < 2*768; i += 256) {
      int b2 = i / 768, d = i - b2*768;
      x_tok[i] = ps[b2][0]*pos_W[d] + ps[b2][1]*pos_W[768 + d]
               + pos_b[d] + te[(size_t)(NPAST + t)*768 + d];
    }
  }
}

// ---------------- host ----------------
extern "C" void kernel_launch(void* const* d_in, const int* in_sizes, int n_in,
                              void* d_out, int out_size, void* d_ws, size_t ws_size,
                              hipStream_t stream) {
  (void)in_sizes; (void)n_in; (void)out_size; (void)ws_size;
  const float* feats   = (const float*)d_in[0];
  const float* past    = (const float*)d_in[1];
  const int*   intent  = (const int*)d_in[2];
  const float* img_pos = (const float*)d_in[3];
  const float* time_e  = (const float*)d_in[4];
  const float* int_emb = (const float*)d_in[5];
  const float* past_W  = (const float*)d_in[6];
  const float* past_b  = (const float*)d_in[7];
  const float* pos_W   = (const float*)d_in[8];
  const float* pos_b   = (const float*)d_in[9];
  const float* ln1_g   = (const float*)d_in[10];
  const float* ln1_b   = (const float*)d_in[11];
  const float* qkv_W   = (const float*)d_in[12];
  const float* qkv_b   = (const float*)d_in[13];
  const float* out_W   = (const float*)d_in[14];
  const float* out_b   = (const float*)d_in[15];
  const float* ln2_g   = (const float*)d_in[16];
  const float* ln2_b   = (const float*)d_in[17];
  const float* ff1_W   = (const float*)d_in[18];
  const float* ff1_b   = (const float*)d_in[19];
  const float* ff2_W   = (const float*)d_in[20];
  const float* ff2_b   = (const float*)d_in[21];
  const float* dec1_W  = (const float*)d_in[22];
  const float* dec1_b  = (const float*)d_in[23];
  const float* dec2_W  = (const float*)d_in[24];
  const float* dec2_b  = (const float*)d_in[25];
  float* outp = (float*)d_out;

  float* ws = (float*)d_ws;
  size_t off = 0;
  float* xbuf = ws + off;   off += (size_t)MM*DD;
  float* hbuf = ws + off;   off += (size_t)MM*DD;
  float* ctxbuf = hbuf;  // alias: h consumed before attention writes ctx
  float* bigbuf = ws + off; off += (size_t)MM*3072;
  float* Kc = ws + off;     off += (size_t)LL*BB*HH*SPAD*HDIM;
  float* Vc = ws + off;     off += (size_t)LL*BB*HH*SPAD*HDIM;
  float* x_tok = ws + off;  off += BB*DD;
  float* hdec = ws + off;   off += BB*DD;
  float* qkv_tok = ws + off; off += BB*2304;
  float* ctx_tok = ws + off; off += BB*DD;
  float* ff_tok = ws + off;  off += BB*3072;

  const size_t KVL = (size_t)BB*HH*SPAD*HDIM;

  // ---- build initial sequence ----
  build_img_kernel<<<dim3(NIMG/64, BB), 256, 0, stream>>>(feats, img_pos, xbuf);
  build_misc_kernel<<<dim3(17, BB), 256, 0, stream>>>(past, intent, int_emb, past_W, past_b, time_e, xbuf);

  // ---- prefill ----
  const int mtiles = (MM + 127) / 128;
  for (int l = 0; l < LL; ++l) {
    float* kcl = Kc + (size_t)l*KVL;
    float* vcl = Vc + (size_t)l*KVL;
    ln_kernel<<<MM, 256, 0, stream>>>(xbuf, ln1_g + l*DD, ln1_b + l*DD, hbuf);
    gemm_f32_kernel<<<dim3(2304/64, mtiles), 256, 0, stream>>>(
        hbuf, qkv_W + (size_t)l*DD*2304, qkv_b + l*2304, bigbuf, MM, 2304, DD, 0);
    scatter_kv_kernel<<<dim3(SEQ0, BB), 256, 0, stream>>>(bigbuf, kcl, vcl, SEQ0, SPAD);
    attn_prefill_kernel<<<dim3((SEQ0 + 31)/32, HH, BB), 256, 0, stream>>>(
        bigbuf, kcl, vcl, ctxbuf, SEQ0, SPAD);
    gemm_f32_kernel<<<dim3(DD/64, mtiles), 256, 0, stream>>>(
        ctxbuf, out_W + (size_t)l*DD*DD, out_b + l*DD, xbuf, MM, DD, DD, 2);
    ln_kernel<<<MM, 256, 0, stream>>>(xbuf, ln2_g + l*DD, ln2_b + l*DD, hbuf);
    gemm_f32_kernel<<<dim3(3072/64, mtiles), 256, 0, stream>>>(
        hbuf, ff1_W + (size_t)l*DD*3072, ff1_b + l*3072, bigbuf, MM, 3072, DD, 1);
    gemm_f32_kernel<<<dim3(DD/64, mtiles), 256, 0, stream>>>(
        bigbuf, ff2_W + (size_t)l*3072*DD, ff2_b + l*DD, xbuf, MM, DD, 3072, 2);
  }

  // ---- head for t=0 ----
  dgemv_kernel<256><<<DD/64, 256, 0, stream>>>(
      xbuf + (size_t)(SEQ0 - 1)*DD, (size_t)SEQ0*DD, dec1_W, dec1_b,
      nullptr, nullptr, hdec, DD, DD, 3, nullptr, nullptr, 0, 0);
  head2_kernel<<<1, 256, 0, stream>>>(hdec, dec2_W, dec2_b, pos_W, pos_b, time_e,
                                      0, outp, x_tok, 1);

  // ---- incremental decode t = 1..19 ----
  for (int t = 1; t < TDEC; ++t) {
    int S = SEQ0 + t;
    int pos = S - 1;
    for (int l = 0; l < LL; ++l) {
      float* kcl = Kc + (size_t)l*KVL;
      float* vcl = Vc + (size_t)l*KVL;
      dgemv_kernel<256><<<2304/64, 256, 0, stream>>>(
          x_tok, (size_t)DD, qkv_W + (size_t)l*DD*2304, qkv_b + l*2304,
          ln1_g + l*DD, ln1_b + l*DD, qkv_tok, DD, 2304, 0, kcl, vcl, pos, SPAD);
      dec_attn_kernel<<<dim3(HH, BB), 256, 0, stream>>>(qkv_tok, kcl, vcl, ctx_tok, S, SPAD);
      dgemv_kernel<256><<<DD/64, 256, 0, stream>>>(
          ctx_tok, (size_t)DD, out_W + (size_t)l*DD*DD, out_b + l*DD,
          nullptr, nullptr, x_tok, DD, DD, 2, nullptr, nullptr, 0, 0);
      dgemv_kernel<256><<<3072/64, 256, 0, stream>>>(
          x_tok, (size_t)DD, ff1_W + (size_t)l*DD*3072, ff1_b + l*3072,
          ln2_g + l*DD, ln2_b + l*DD, ff_tok, DD, 3072, 1, nullptr, nullptr, 0, 0);
      dgemv_kernel<512><<<DD/64, 512, 0, stream>>>(
          ff_tok, (size_t)3072, ff2_W + (size_t)l*3072*DD, ff2_b + l*DD,
          nullptr, nullptr, x_tok, 3072, DD, 2, nullptr, nullptr, 0, 0);
    }
    dgemv_kernel<256><<<DD/64, 256, 0, stream>>>(
        x_tok, (size_t)DD, dec1_W, dec1_b, nullptr, nullptr,
        hdec, DD, DD, 3, nullptr, nullptr, 0, 0);
    head2_kernel<<<1, 256, 0, stream>>>(hdec, dec2_W, dec2_b, pos_W, pos_b, time_e,
                                        t, outp, x_tok, (t < TDEC - 1) ? 1 : 0);
  }
}

// Round 3
// 7624.891 us; speedup vs baseline: 2.5863x; 1.1200x over previous
//
#include <hip/hip_runtime.h>
#include <math.h>

#define BB 2
#define DD 768
#define HH 16
#define HDIM 48
#define LL 3
#define NIMG 1024
#define NPAST 16
#define TDEC 20
#define SEQ0 1041
#define SPAD 1064
#define MM (BB*SEQ0)
#define SCALE_QK 0.14433756729740643f

typedef __attribute__((ext_vector_type(4))) float f32x4;
typedef __attribute__((ext_vector_type(8))) short bf16x8;

__device__ __forceinline__ short f2bf(float x) {
  unsigned u = __float_as_uint(x);
  unsigned r = (u + 0x7FFFu + ((u >> 16) & 1u)) >> 16;
  return (short)r;
}
__device__ __forceinline__ float bf2f(short h) {
  return __uint_as_float(((unsigned)(unsigned short)h) << 16);
}

// ---------------- utils ----------------
__device__ __forceinline__ float block_sum256(float v, float* red) {
#pragma unroll
  for (int off = 32; off; off >>= 1) v += __shfl_down(v, off);
  __syncthreads();
  if ((threadIdx.x & 63) == 0) red[threadIdx.x >> 6] = v;
  __syncthreads();
  return red[0] + red[1] + red[2] + red[3];
}

// ---------------- build sequence ----------------
__global__ __launch_bounds__(256) void build_img_kernel(
    const float* __restrict__ feats, const float* __restrict__ pe, float* __restrict__ x)
{
  __shared__ float T[64][65];
  int b = blockIdx.y;
  int s0 = blockIdx.x * 64;
  int tid = threadIdx.x;
  int r = tid >> 2;
  int c0 = (tid & 3) << 4;
  for (int d0 = 0; d0 < 768; d0 += 64) {
    const float* fp = feats + ((size_t)b*768 + d0 + r)*1024 + s0 + c0;
#pragma unroll
    for (int i = 0; i < 16; ++i) T[r][c0 + i] = fp[i];
    __syncthreads();
    float* xp = x + ((size_t)(b*SEQ0 + s0 + r))*768 + d0 + c0;
    const float* pp = pe + (size_t)(s0 + r)*768 + d0 + c0;
#pragma unroll
    for (int i = 0; i < 16; ++i) xp[i] = T[c0 + i][r] + pp[i];
    __syncthreads();
  }
}

__global__ __launch_bounds__(256) void build_misc_kernel(
    const float* __restrict__ past, const int* __restrict__ intent,
    const float* __restrict__ int_emb, const float* __restrict__ past_W,
    const float* __restrict__ past_b, const float* __restrict__ te,
    float* __restrict__ x)
{
  int b = blockIdx.y;
  int i = blockIdx.x;  // 0..16
  int tid = threadIdx.x;
  if (i == 0) {
    int idx = intent[b] - 1;
    idx = max(0, min(2, idx));
    for (int d = tid; d < 768; d += 256)
      x[((size_t)(b*SEQ0 + 1024))*768 + d] = int_emb[idx*768 + d];
  } else {
    int pi = i - 1;
    float p0 = past[(b*NPAST + pi)*6 + 0], p1 = past[(b*NPAST + pi)*6 + 1];
    float p2 = past[(b*NPAST + pi)*6 + 2], p3 = past[(b*NPAST + pi)*6 + 3];
    float p4 = past[(b*NPAST + pi)*6 + 4], p5 = past[(b*NPAST + pi)*6 + 5];
    for (int d = tid; d < 768; d += 256) {
      float s = past_b[d] + te[(size_t)pi*768 + d];
      s += p0*past_W[0*768 + d] + p1*past_W[1*768 + d] + p2*past_W[2*768 + d];
      s += p3*past_W[3*768 + d] + p4*past_W[4*768 + d] + p5*past_W[5*768 + d];
      x[((size_t)(b*SEQ0 + 1025 + pi))*768 + d] = s;
    }
  }
}

// ---------------- layernorm (prefill) ----------------
__global__ __launch_bounds__(256) void ln_kernel(
    const float* __restrict__ x, const float* __restrict__ g,
    const float* __restrict__ bta, float* __restrict__ h)
{
  __shared__ float red[4];
  size_t row = blockIdx.x;
  const float* xr = x + row*768;
  float* hr = h + row*768;
  int tid = threadIdx.x;
  float v0 = xr[tid], v1 = xr[tid+256], v2 = xr[tid+512];
  float m = block_sum256(v0+v1+v2, red) * (1.f/768.f);
  float d0 = v0-m, d1 = v1-m, d2 = v2-m;
  float var = block_sum256(d0*d0 + d1*d1 + d2*d2, red) * (1.f/768.f);
  float inv = rsqrtf(var + 1e-5f);
  hr[tid]     = d0*inv*g[tid]     + bta[tid];
  hr[tid+256] = d1*inv*g[tid+256] + bta[tid+256];
  hr[tid+512] = d2*inv*g[tid+512] + bta[tid+512];
}

// ---------------- W convert+transpose: fp32 [K][N] -> bf16 hi/lo [N][K] ----------------
__global__ __launch_bounds__(256) void wconv_kernel(
    const float* __restrict__ W, short* __restrict__ th, short* __restrict__ tl,
    int K, int N)
{
  __shared__ float T[64][68];
  int n0 = blockIdx.x * 64, k0 = blockIdx.y * 64;
  int t = threadIdx.x;
  int r = t >> 2, c0 = (t & 3) * 16;
  const float* src = W + (size_t)(k0 + r)*N + n0 + c0;
#pragma unroll
  for (int j = 0; j < 4; ++j) {
    f32x4 v = *(const f32x4*)(src + 4*j);
    T[r][c0 + 4*j + 0] = v.x; T[r][c0 + 4*j + 1] = v.y;
    T[r][c0 + 4*j + 2] = v.z; T[r][c0 + 4*j + 3] = v.w;
  }
  __syncthreads();
  // output row n = n0 + r, k chunk [k0+c0, k0+c0+16)
  bf16x8 h0, h1, l0, l1;
#pragma unroll
  for (int i = 0; i < 8; ++i) {
    float x = T[c0 + i][r];
    short hh = f2bf(x);
    h0[i] = hh; l0[i] = f2bf(x - bf2f(hh));
    float y = T[c0 + 8 + i][r];
    short hy = f2bf(y);
    h1[i] = hy; l1[i] = f2bf(y - bf2f(hy));
  }
  size_t dst = (size_t)(n0 + r)*K + k0 + c0;
  *(bf16x8*)(th + dst) = h0;
  *(bf16x8*)(th + dst + 8) = h1;
  *(bf16x8*)(tl + dst) = l0;
  *(bf16x8*)(tl + dst + 8) = l1;
}

// ---------------- MFMA GEMM: C(M,N) = A(M,K) @ W(K,N) + bias ----------------
// A fp32 (converted to bf16 hi/lo during staging); W pre-converted bf16 [N][K] hi/lo.
// 3-pass: Ah*Wh + Ah*Wl + Al*Wh. mode: 0 store, 1 relu, 2 add-into-C
__global__ __launch_bounds__(256) void gemm_mfma_kernel(
    const float* __restrict__ A, const short* __restrict__ Wh,
    const short* __restrict__ Wl, const float* __restrict__ bias,
    float* __restrict__ C, int M, int N, int K, int mode)
{
  __shared__ short As[2][128][40];   // [hi/lo][m][k]
  __shared__ short Bs[2][128][40];   // [hi/lo][n][k]
  int tid = threadIdx.x;
  int n0 = blockIdx.x * 128, m0 = blockIdx.y * 128;
  int wid = tid >> 6, l = tid & 63;
  int wm = wid >> 1, wn = wid & 1;
  int fr = l & 15, fk = (l >> 4) * 8;
  f32x4 acc[4][4] = {};
  int arow = tid >> 1, akh = (tid & 1) * 16;
  const float* aptr = A + (size_t)(m0 + arow)*K + akh;
  bool aval = (m0 + arow) < M;

  for (int k0 = 0; k0 < K; k0 += 32) {
    // ---- stage A (fp32 -> bf16 hi/lo) ----
    {
      float xv[16];
      if (aval) {
        const float* ap = aptr + k0;
#pragma unroll
        for (int j = 0; j < 4; ++j) {
          f32x4 v = *(const f32x4*)(ap + 4*j);
          xv[4*j+0] = v.x; xv[4*j+1] = v.y; xv[4*j+2] = v.z; xv[4*j+3] = v.w;
        }
      } else {
#pragma unroll
        for (int j = 0; j < 16; ++j) xv[j] = 0.f;
      }
      bf16x8 h0, h1, l0, l1;
#pragma unroll
      for (int e = 0; e < 8; ++e) {
        short hh = f2bf(xv[e]);
        h0[e] = hh; l0[e] = f2bf(xv[e] - bf2f(hh));
        short hy = f2bf(xv[8+e]);
        h1[e] = hy; l1[e] = f2bf(xv[8+e] - bf2f(hy));
      }
      *(bf16x8*)&As[0][arow][akh]     = h0;
      *(bf16x8*)&As[0][arow][akh + 8] = h1;
      *(bf16x8*)&As[1][arow][akh]     = l0;
      *(bf16x8*)&As[1][arow][akh + 8] = l1;
    }
    // ---- stage W (already bf16 [N][K]) ----
#pragma unroll
    for (int cc = 0; cc < 2; ++cc) {
      int c = tid + cc*256;
      int row = c >> 2, woff = (c & 3) * 8;
      size_t src = (size_t)(n0 + row)*K + k0 + woff;
      *(bf16x8*)&Bs[0][row][woff] = *(const bf16x8*)(Wh + src);
      *(bf16x8*)&Bs[1][row][woff] = *(const bf16x8*)(Wl + src);
    }
    __syncthreads();
    // ---- fragments + MFMA ----
    bf16x8 af[4][2], bfv[4][2];
#pragma unroll
    for (int i = 0; i < 4; ++i) {
#pragma unroll
      for (int p = 0; p < 2; ++p) {
        af[i][p]  = *(const bf16x8*)&As[p][wm*64 + i*16 + fr][fk];
        bfv[i][p] = *(const bf16x8*)&Bs[p][wn*64 + i*16 + fr][fk];
      }
    }
#pragma unroll
    for (int im = 0; im < 4; ++im) {
#pragma unroll
      for (int in = 0; in < 4; ++in) {
        acc[im][in] = __builtin_amdgcn_mfma_f32_16x16x32_bf16(af[im][0], bfv[in][0], acc[im][in], 0, 0, 0);
        acc[im][in] = __builtin_amdgcn_mfma_f32_16x16x32_bf16(af[im][0], bfv[in][1], acc[im][in], 0, 0, 0);
        acc[im][in] = __builtin_amdgcn_mfma_f32_16x16x32_bf16(af[im][1], bfv[in][0], acc[im][in], 0, 0, 0);
      }
    }
    __syncthreads();
  }
  // ---- epilogue: D col = lane&15 (n), row = (lane>>4)*4 + reg (m) ----
#pragma unroll
  for (int in = 0; in < 4; ++in) {
    int n = n0 + wn*64 + in*16 + (l & 15);
    float bv = bias[n];
#pragma unroll
    for (int im = 0; im < 4; ++im) {
      f32x4 v = acc[im][in];
#pragma unroll
      for (int r = 0; r < 4; ++r) {
        int m = m0 + wm*64 + im*16 + (l >> 4)*4 + r;
        if (m < M) {
          float x = v[r] + bv;
          float* cp = &C[(size_t)m*N + n];
          if (mode == 1) x = fmaxf(x, 0.f);
          if (mode == 2) x += *cp;
          *cp = x;
        }
      }
    }
  }
}

// ---------------- scatter K/V into cache (prefill) ----------------
__global__ __launch_bounds__(256) void scatter_kv_kernel(
    const float* __restrict__ qkv, float* __restrict__ kc, float* __restrict__ vc,
    int S, int spad)
{
  int s = blockIdx.x, b = blockIdx.y;
  const float* row = qkv + ((size_t)b*S + s)*2304;
  int tid = threadIdx.x;
#pragma unroll
  for (int i = 0; i < 3; ++i) {
    int j = tid + i*256;
    int hh = j / 48, hd = j - hh*48;
    size_t dst = ((size_t)(b*16 + hh)*spad + s)*48 + hd;
    kc[dst] = row[768 + j];
    vc[dst] = row[1536 + j];
  }
}

// ---------------- causal flash attention (prefill), 32-row Q tiles ----------------
__global__ __launch_bounds__(256) void attn_prefill_kernel(
    const float* __restrict__ qkv, const float* __restrict__ Kc,
    const float* __restrict__ Vc, float* __restrict__ ctx, int S, int spad)
{
  __shared__ float Qs[32][49];
  __shared__ float Ks[64][49];
  __shared__ float Vs[64][49];
  __shared__ float Ps[32][65];
  __shared__ float mrow[32], lrow[32], resc[32];
  int tid = threadIdx.x;
  int qt = blockIdx.x, h = blockIdx.y, b = blockIdx.z;
  int q0 = qt * 32;
  for (int i = tid; i < 32*48; i += 256) {
    int r = i / 48, d = i - r*48;
    int s = q0 + r;
    Qs[r][d] = (s < S) ? qkv[((size_t)(b*S + s))*2304 + h*48 + d] * SCALE_QK : 0.f;
  }
  if (tid < 32) { mrow[tid] = -INFINITY; lrow[tid] = 0.f; }
  float acc[2][3] = {};
  int pr0 = (tid >> 4) << 1;
  int pc  = tid & 15;
  int sr  = tid & 31;
  int skg = tid >> 5;
  int q_last = min(q0 + 31, S - 1);
  const float* Kb = Kc + (size_t)(b*16 + h)*spad*48;
  const float* Vb = Vc + (size_t)(b*16 + h)*spad*48;
  __syncthreads();
  float qreg[48];
#pragma unroll
  for (int d = 0; d < 48; ++d) qreg[d] = Qs[sr][d];
  for (int k0 = 0; k0 <= q_last; k0 += 64) {
    int kn = min(64, q_last - k0 + 1);
    for (int i = tid; i < 64*48; i += 256) {
      int r = i / 48, d = i - r*48;
      bool ok = r < kn;
      Ks[r][d] = ok ? Kb[(size_t)(k0 + r)*48 + d] : 0.f;
      Vs[r][d] = ok ? Vb[(size_t)(k0 + r)*48 + d] : 0.f;
    }
    __syncthreads();
    {
      int qg = q0 + sr;
#pragma unroll
      for (int jj = 0; jj < 8; ++jj) {
        int k = skg*8 + jj;
        float s = 0.f;
#pragma unroll
        for (int d = 0; d < 48; ++d) s += qreg[d] * Ks[k][d];
        int kg = k0 + k;
        bool valid = (qg < S) && (k < kn) && (kg <= qg);
        Ps[sr][k] = valid ? s : -INFINITY;
      }
    }
    __syncthreads();
    if (tid < 32) {
      int r = tid;
      float mold = mrow[r];
      float mx = mold;
#pragma unroll 8
      for (int k = 0; k < 64; ++k) mx = fmaxf(mx, Ps[r][k]);
      float rs = 1.f;
      if (mx > -INFINITY) {
        rs = (mold > -INFINITY) ? __expf(mold - mx) : 0.f;
        float psum = 0.f;
#pragma unroll 8
        for (int k = 0; k < 64; ++k) {
          float p = __expf(Ps[r][k] - mx);
          Ps[r][k] = p;
          psum += p;
        }
        lrow[r] = lrow[r]*rs + psum;
        mrow[r] = mx;
      } else {
#pragma unroll 8
        for (int k = 0; k < 64; ++k) Ps[r][k] = 0.f;
        rs = 1.f;
      }
      resc[r] = rs;
    }
    __syncthreads();
#pragma unroll
    for (int rr = 0; rr < 2; ++rr) {
      int r = pr0 + rr;
      float f = resc[r];
      float a0 = acc[rr][0]*f, a1 = acc[rr][1]*f, a2 = acc[rr][2]*f;
#pragma unroll 16
      for (int k = 0; k < 64; ++k) {
        float p = Ps[r][k];
        a0 += p * Vs[k][pc*3+0];
        a1 += p * Vs[k][pc*3+1];
        a2 += p * Vs[k][pc*3+2];
      }
      acc[rr][0] = a0; acc[rr][1] = a1; acc[rr][2] = a2;
    }
    __syncthreads();
  }
#pragma unroll
  for (int rr = 0; rr < 2; ++rr) {
    int r = pr0 + rr, s = q0 + r;
    if (s < S) {
      float invl = 1.f / lrow[r];
      float* cp = &ctx[((size_t)(b*S + s))*768 + h*48 + pc*3];
      cp[0] = acc[rr][0]*invl; cp[1] = acc[rr][1]*invl; cp[2] = acc[rr][2]*invl;
    }
  }
}

// ---------------- decode GEMV: B=2 fused, K-split within block ----------------
template<int NT>
__global__ __launch_bounds__(NT) void dgemv_kernel(
    const float* __restrict__ xin, size_t in_stride,
    const float* __restrict__ W, const float* __restrict__ bias,
    const float* __restrict__ ln_g, const float* __restrict__ ln_b,
    float* __restrict__ out, int K, int N, int mode,
    float* __restrict__ kc, float* __restrict__ vc, int pos, int spad)
{
  constexpr int SEGS = NT / 64;
  __shared__ float hs[2][3072];
  __shared__ float part[8][2][64];
  __shared__ float red[4];
  int tid = threadIdx.x;
  if (NT == 256 && ln_g) {  // K == 768
#pragma unroll
    for (int b = 0; b < 2; ++b) {
      const float* xr = xin + (size_t)b * in_stride;
      float v0 = xr[tid], v1 = xr[tid+256], v2 = xr[tid+512];
      float m = block_sum256(v0+v1+v2, red) * (1.f/768.f);
      float d0 = v0-m, d1 = v1-m, d2 = v2-m;
      float var = block_sum256(d0*d0 + d1*d1 + d2*d2, red) * (1.f/768.f);
      float inv = rsqrtf(var + 1e-5f);
      hs[b][tid]     = d0*inv*ln_g[tid]     + ln_b[tid];
      hs[b][tid+256] = d1*inv*ln_g[tid+256] + ln_b[tid+256];
      hs[b][tid+512] = d2*inv*ln_g[tid+512] + ln_b[tid+512];
    }
  } else {
#pragma unroll
    for (int b = 0; b < 2; ++b) {
      const float* xr = xin + (size_t)b * in_stride;
      for (int k = tid; k < K; k += NT) hs[b][k] = xr[k];
    }
  }
  __syncthreads();
  int lane = tid & 63, seg = tid >> 6;
  int n = blockIdx.x * 64 + lane;
  int chunk = K / SEGS;
  int k0 = seg * chunk;
  const float* wp = W + n;
  float a0 = 0.f, a1 = 0.f;
  for (int k = k0; k < k0 + chunk; k += 8) {
#pragma unroll
    for (int u = 0; u < 8; ++u) {
      float w = wp[(size_t)(k+u)*N];
      a0 += hs[0][k+u] * w;
      a1 += hs[1][k+u] * w;
    }
  }
  part[seg][0][lane] = a0;
  part[seg][1][lane] = a1;
  __syncthreads();
  if (tid < 128) {
    int b = tid >> 6, l = tid & 63;
    int nn = blockIdx.x * 64 + l;
    float v = bias[nn];
#pragma unroll
    for (int s = 0; s < SEGS; ++s) v += part[s][b][l];
    if (mode == 1) v = fmaxf(v, 0.f);
    else if (mode == 3) v = 0.5f*v*(1.f + erff(v*0.70710678118654752f));
    if (mode == 2) out[(size_t)b*N + nn] += v;
    else out[(size_t)b*N + nn] = v;
    if (kc) {
      if (nn >= 768 && nn < 1536) {
        int j = nn - 768;
        kc[((size_t)(b*16 + j/48)*spad + pos)*48 + (j % 48)] = v;
      } else if (nn >= 1536) {
        int j = nn - 1536;
        vc[((size_t)(b*16 + j/48)*spad + pos)*48 + (j % 48)] = v;
      }
    }
  }
}

// ---------------- decode attention (single new token) ----------------
__global__ __launch_bounds__(256) void dec_attn_kernel(
    const float* __restrict__ qkv_tok, const float* __restrict__ Kc,
    const float* __restrict__ Vc, float* __restrict__ ctx_tok, int S, int spad)
{
  __shared__ float qs[48];
  __shared__ float redm[4];
  __shared__ float reds[4];
  __shared__ float aw[4][48];
  int tid = threadIdx.x;
  int h = blockIdx.x, b = blockIdx.y;
  if (tid < 48) qs[tid] = qkv_tok[b*2304 + h*48 + tid] * SCALE_QK;
  __syncthreads();
  const float* Kb = Kc + (size_t)(b*16 + h)*spad*48;
  const float* Vb = Vc + (size_t)(b*16 + h)*spad*48;
  float ls[5];
  int cnt = 0;
  float lmax = -INFINITY;
  for (int k = tid; k < S; k += 256) {
    const float4* kr = (const float4*)(Kb + (size_t)k*48);
    float s = 0.f;
#pragma unroll
    for (int i = 0; i < 12; ++i) {
      float4 kv = kr[i];
      s += qs[4*i+0]*kv.x + qs[4*i+1]*kv.y + qs[4*i+2]*kv.z + qs[4*i+3]*kv.w;
    }
    ls[cnt++] = s;
    lmax = fmaxf(lmax, s);
  }
#pragma unroll
  for (int off = 32; off; off >>= 1) lmax = fmaxf(lmax, __shfl_down(lmax, off));
  if ((tid & 63) == 0) redm[tid >> 6] = lmax;
  __syncthreads();
  float M = fmaxf(fmaxf(redm[0], redm[1]), fmaxf(redm[2], redm[3]));
  float lsum = 0.f;
  float4 a[12];
#pragma unroll
  for (int i = 0; i < 12; ++i) a[i] = make_float4(0.f, 0.f, 0.f, 0.f);
  cnt = 0;
  for (int k = tid; k < S; k += 256) {
    float p = __expf(ls[cnt++] - M);
    lsum += p;
    const float4* vr = (const float4*)(Vb + (size_t)k*48);
#pragma unroll
    for (int i = 0; i < 12; ++i) {
      float4 vv = vr[i];
      a[i].x += p*vv.x; a[i].y += p*vv.y; a[i].z += p*vv.z; a[i].w += p*vv.w;
    }
  }
  float tot = block_sum256(lsum, reds);
#pragma unroll
  for (int i = 0; i < 12; ++i) {
    float x0 = a[i].x, x1 = a[i].y, x2 = a[i].z, x3 = a[i].w;
#pragma unroll
    for (int off = 32; off; off >>= 1) {
      x0 += __shfl_down(x0, off); x1 += __shfl_down(x1, off);
      x2 += __shfl_down(x2, off); x3 += __shfl_down(x3, off);
    }
    if ((tid & 63) == 0) {
      int w = tid >> 6;
      aw[w][4*i+0] = x0; aw[w][4*i+1] = x1; aw[w][4*i+2] = x2; aw[w][4*i+3] = x3;
    }
  }
  __syncthreads();
  if (tid < 48) {
    float s = aw[0][tid] + aw[1][tid] + aw[2][tid] + aw[3][tid];
    ctx_tok[b*768 + h*48 + tid] = s / tot;
  }
}

// ---------------- head stage 2 ----------------
__global__ __launch_bounds__(256) void head2_kernel(
    const float* __restrict__ hdec, const float* __restrict__ dec2_W,
    const float* __restrict__ dec2_b, const float* __restrict__ pos_W,
    const float* __restrict__ pos_b, const float* __restrict__ te,
    int t, float* __restrict__ outp, float* __restrict__ x_tok, int write_next)
{
  __shared__ float ps[2][2];
  int tid = threadIdx.x;
  int w = tid >> 6, lane = tid & 63;
  int b = w >> 1, j = w & 1;
  float partial = 0.f;
  for (int k = lane; k < 768; k += 64) partial += hdec[b*768 + k] * dec2_W[k*2 + j];
#pragma unroll
  for (int off = 32; off; off >>= 1) partial += __shfl_down(partial, off);
  if (lane == 0) {
    float v = partial + dec2_b[j];
    ps[b][j] = v;
    outp[(b*TDEC + t)*2 + j] = v;
  }
  __syncthreads();
  if (write_next) {
    for (int i = tid; i < 2*768; i += 256) {
      int b2 = i / 768, d = i - b2*768;
      x_tok[i] = ps[b2][0]*pos_W[d] + ps[b2][1]*pos_W[768 + d]
               + pos_b[d] + te[(size_t)(NPAST + t)*768 + d];
    }
  }
}

// ---------------- host ----------------
extern "C" void kernel_launch(void* const* d_in, const int* in_sizes, int n_in,
                              void* d_out, int out_size, void* d_ws, size_t ws_size,
                              hipStream_t stream) {
  (void)in_sizes; (void)n_in; (void)out_size; (void)ws_size;
  const float* feats   = (const float*)d_in[0];
  const float* past    = (const float*)d_in[1];
  const int*   intent  = (const int*)d_in[2];
  const float* img_pos = (const float*)d_in[3];
  const float* time_e  = (const float*)d_in[4];
  const float* int_emb = (const float*)d_in[5];
  const float* past_W  = (const float*)d_in[6];
  const float* past_b  = (const float*)d_in[7];
  const float* pos_W   = (const float*)d_in[8];
  const float* pos_b   = (const float*)d_in[9];
  const float* ln1_g   = (const float*)d_in[10];
  const float* ln1_b   = (const float*)d_in[11];
  const float* qkv_W   = (const float*)d_in[12];
  const float* qkv_b   = (const float*)d_in[13];
  const float* out_W   = (const float*)d_in[14];
  const float* out_b   = (const float*)d_in[15];
  const float* ln2_g   = (const float*)d_in[16];
  const float* ln2_b   = (const float*)d_in[17];
  const float* ff1_W   = (const float*)d_in[18];
  const float* ff1_b   = (const float*)d_in[19];
  const float* ff2_W   = (const float*)d_in[20];
  const float* ff2_b   = (const float*)d_in[21];
  const float* dec1_W  = (const float*)d_in[22];
  const float* dec1_b  = (const float*)d_in[23];
  const float* dec2_W  = (const float*)d_in[24];
  const float* dec2_b  = (const float*)d_in[25];
  float* outp = (float*)d_out;

  float* ws = (float*)d_ws;
  size_t off = 0;
  float* xbuf = ws + off;   off += (size_t)MM*DD;
  float* hbuf = ws + off;   off += (size_t)MM*DD;
  float* ctxbuf = hbuf;  // alias: h consumed before attention writes ctx
  float* bigbuf = ws + off; off += (size_t)MM*3072;
  float* Kc = ws + off;     off += (size_t)LL*BB*HH*SPAD*HDIM;
  float* Vc = ws + off;     off += (size_t)LL*BB*HH*SPAD*HDIM;
  float* x_tok = ws + off;  off += BB*DD;
  float* hdec = ws + off;   off += BB*DD;
  float* qkv_tok = ws + off; off += BB*2304;
  float* ctx_tok = ws + off; off += BB*DD;
  float* ff_tok = ws + off;  off += BB*3072;
  // bf16 hi/lo transposed-weight scratch (reused per weight): max 768*3072 shorts each
  short* wt_h = (short*)(ws + off); off += (size_t)768*3072/2;
  short* wt_l = (short*)(ws + off); off += (size_t)768*3072/2;

  const size_t KVL = (size_t)BB*HH*SPAD*HDIM;

  // ---- build initial sequence ----
  build_img_kernel<<<dim3(NIMG/64, BB), 256, 0, stream>>>(feats, img_pos, xbuf);
  build_misc_kernel<<<dim3(17, BB), 256, 0, stream>>>(past, intent, int_emb, past_W, past_b, time_e, xbuf);

  // ---- prefill ----
  const int mtiles = (MM + 127) / 128;  // 17
  for (int l = 0; l < LL; ++l) {
    float* kcl = Kc + (size_t)l*KVL;
    float* vcl = Vc + (size_t)l*KVL;

    ln_kernel<<<MM, 256, 0, stream>>>(xbuf, ln1_g + l*DD, ln1_b + l*DD, hbuf);
    wconv_kernel<<<dim3(2304/64, 768/64), 256, 0, stream>>>(
        qkv_W + (size_t)l*DD*2304, wt_h, wt_l, DD, 2304);
    gemm_mfma_kernel<<<dim3(2304/128, mtiles), 256, 0, stream>>>(
        hbuf, wt_h, wt_l, qkv_b + l*2304, bigbuf, MM, 2304, DD, 0);

    scatter_kv_kernel<<<dim3(SEQ0, BB), 256, 0, stream>>>(bigbuf, kcl, vcl, SEQ0, SPAD);
    attn_prefill_kernel<<<dim3((SEQ0 + 31)/32, HH, BB), 256, 0, stream>>>(
        bigbuf, kcl, vcl, ctxbuf, SEQ0, SPAD);

    wconv_kernel<<<dim3(768/64, 768/64), 256, 0, stream>>>(
        out_W + (size_t)l*DD*DD, wt_h, wt_l, DD, 768);
    gemm_mfma_kernel<<<dim3(768/128, mtiles), 256, 0, stream>>>(
        ctxbuf, wt_h, wt_l, out_b + l*DD, xbuf, MM, 768, DD, 2);

    ln_kernel<<<MM, 256, 0, stream>>>(xbuf, ln2_g + l*DD, ln2_b + l*DD, hbuf);
    wconv_kernel<<<dim3(3072/64, 768/64), 256, 0, stream>>>(
        ff1_W + (size_t)l*DD*3072, wt_h, wt_l, DD, 3072);
    gemm_mfma_kernel<<<dim3(3072/128, mtiles), 256, 0, stream>>>(
        hbuf, wt_h, wt_l, ff1_b + l*3072, bigbuf, MM, 3072, DD, 1);

    wconv_kernel<<<dim3(768/64, 3072/64), 256, 0, stream>>>(
        ff2_W + (size_t)l*3072*DD, wt_h, wt_l, 3072, 768);
    gemm_mfma_kernel<<<dim3(768/128, mtiles), 256, 0, stream>>>(
        bigbuf, wt_h, wt_l, ff2_b + l*DD, xbuf, MM, 768, 3072, 2);
  }

  // ---- head for t=0 ----
  dgemv_kernel<256><<<DD/64, 256, 0, stream>>>(
      xbuf + (size_t)(SEQ0 - 1)*DD, (size_t)SEQ0*DD, dec1_W, dec1_b,
      nullptr, nullptr, hdec, DD, DD, 3, nullptr, nullptr, 0, 0);
  head2_kernel<<<1, 256, 0, stream>>>(hdec, dec2_W, dec2_b, pos_W, pos_b, time_e,
                                      0, outp, x_tok, 1);

  // ---- incremental decode t = 1..19 ----
  for (int t = 1; t < TDEC; ++t) {
    int S = SEQ0 + t;
    int pos = S - 1;
    for (int l = 0; l < LL; ++l) {
      float* kcl = Kc + (size_t)l*KVL;
      float* vcl = Vc + (size_t)l*KVL;
      dgemv_kernel<256><<<2304/64, 256, 0, stream>>>(
          x_tok, (size_t)DD, qkv_W + (size_t)l*DD*2304, qkv_b + l*2304,
          ln1_g + l*DD, ln1_b + l*DD, qkv_tok, DD, 2304, 0, kcl, vcl, pos, SPAD);
      dec_attn_kernel<<<dim3(HH, BB), 256, 0, stream>>>(qkv_tok, kcl, vcl, ctx_tok, S, SPAD);
      dgemv_kernel<256><<<DD/64, 256, 0, stream>>>(
          ctx_tok, (size_t)DD, out_W + (size_t)l*DD*DD, out_b + l*DD,
          nullptr, nullptr, x_tok, DD, DD, 2, nullptr, nullptr, 0, 0);
      dgemv_kernel<256><<<3072/64, 256, 0, stream>>>(
          x_tok, (size_t)DD, ff1_W + (size_t)l*DD*3072, ff1_b + l*3072,
          ln2_g + l*DD, ln2_b + l*DD, ff_tok, DD, 3072, 1, nullptr, nullptr, 0, 0);
      dgemv_kernel<512><<<DD/64, 512, 0, stream>>>(
          ff_tok, (size_t)3072, ff2_W + (size_t)l*3072*DD, ff2_b + l*DD,
          nullptr, nullptr, x_tok, 3072, DD, 2, nullptr, nullptr, 0, 0);
    }
    dgemv_kernel<256><<<DD/64, 256, 0, stream>>>(
        x_tok, (size_t)DD, dec1_W, dec1_b, nullptr, nullptr,
        hdec, DD, DD, 3, nullptr, nullptr, 0, 0);
    head2_kernel<<<1, 256, 0, stream>>>(hdec, dec2_W, dec2_b, pos_W, pos_b, time_e,
                                        t, outp, x_tok, (t < TDEC - 1) ? 1 : 0);
  }
}